// Round 4
// baseline (122.505 us; speedup 1.0000x reference)
//
#include <hip/hip_runtime.h>

typedef _Float16 half8 __attribute__((ext_vector_type(8)));
typedef _Float16 h16 __attribute__((ext_vector_type(16)));
typedef float f32x4 __attribute__((ext_vector_type(4)));

#define DIN 512
#define DOUT 128
#define BTOT 8192
#define NCHUNK 68                 // 64 spline + 4 skip chunks of BK=128
#define NSPL 8
#define BM 128
#define CHUNK_BYTES 32768         // 16 p-slabs x 128 rows x 16 B
#define CBASE 32768
#define LDS_BYTES 65536

// async global->LDS, 16B/lane (lds dst is wave-uniform; HW adds lane*16)
__device__ static inline void llds16(const char* g, char* l) {
  __builtin_amdgcn_global_load_lds(
      (const __attribute__((address_space(1))) unsigned int*)g,
      (__attribute__((address_space(3))) unsigned int*)l, 16, 0, 0);
}

__device__ static inline unsigned short f2h(float x) {
  _Float16 h = (_Float16)x;
  return __builtin_bit_cast(unsigned short, h);
}

// ---------------- prep 1: pack W_aug (f16) into [chunk][p][o] granules ----------------
__global__ __launch_bounds__(256) void build_wpp(const float* __restrict__ w,
                                                 const float* __restrict__ sk,
                                                 unsigned short* __restrict__ wpp) {
  const int gid = blockIdx.x * 256 + threadIdx.x;   // < 68*2048
  const int g = gid >> 11;
  const int rem = gid & 2047;
  const int p = rem >> 7;
  const int o = rem & 127;
  const int kglob = g * 128 + p * 8;
  const float* src = (kglob < 8192) ? (w + (size_t)o * 8192 + kglob)
                                    : (sk + (size_t)o * 512 + (kglob - 8192));
  const float4 v0 = ((const float4*)src)[0];
  const float4 v1 = ((const float4*)src)[1];
  uint4 pk;
  pk.x = f2h(v0.x) | ((unsigned)f2h(v0.y) << 16);
  pk.y = f2h(v0.z) | ((unsigned)f2h(v0.w) << 16);
  pk.z = f2h(v1.x) | ((unsigned)f2h(v1.y) << 16);
  pk.w = f2h(v1.z) | ((unsigned)f2h(v1.w) << 16);
  ((uint4*)wpp)[gid] = pk;
}

// ---------------- prep 2: x (8192x512 f32) -> xt (512x8192 f16) ----------------
__global__ __launch_bounds__(256) void xpose(const float* __restrict__ x,
                                             _Float16* __restrict__ xt) {
  __shared__ _Float16 t[32][33];
  const int c0 = blockIdx.x * 32;   // i block (16)
  const int r0 = blockIdx.y * 32;   // b block (256)
  const int tx = threadIdx.x & 31, ty = threadIdx.x >> 5;
#pragma unroll
  for (int j = 0; j < 32; j += 8)
    t[ty + j][tx] = (_Float16)x[(size_t)(r0 + ty + j) * DIN + c0 + tx];
  __syncthreads();
#pragma unroll
  for (int j = 0; j < 32; j += 8)
    xt[(size_t)(c0 + ty + j) * BTOT + r0 + tx] = t[tx][ty + j];
}

// ---------------- main: fused C-build + f16 MFMA GEMM ----------------
// grid 512 = 64 b-tiles x 8 k-splits; block 256 = 4 waves, wave-tile 64x64
__global__ __launch_bounds__(256, 2) void kan_mfma(
    const float* __restrict__ x, const _Float16* __restrict__ xt,
    const unsigned short* __restrict__ wpp, const float* __restrict__ bias,
    float* __restrict__ out) {
  __shared__ __align__(16) char smem[LDS_BYTES];  // [0,32K): W ; [32K,64K): C
  const int tid = threadIdx.x;
  const int bt = blockIdx.x >> 3;
  const int sp = blockIdx.x & 7;
  const int b0 = bt * BM;
  const int wid = tid >> 6, lane = tid & 63;
  const int lr = lane & 15, lq = lane >> 4;
  const int wm = wid & 1, wn = wid >> 1;

  const h16 iota16 = {(_Float16)0, (_Float16)1, (_Float16)2, (_Float16)3,
                      (_Float16)4, (_Float16)5, (_Float16)6, (_Float16)7,
                      (_Float16)8, (_Float16)9, (_Float16)10, (_Float16)11,
                      (_Float16)12, (_Float16)13, (_Float16)14, (_Float16)15};
  const h16 one16 = {(_Float16)1, (_Float16)1, (_Float16)1, (_Float16)1,
                     (_Float16)1, (_Float16)1, (_Float16)1, (_Float16)1,
                     (_Float16)1, (_Float16)1, (_Float16)1, (_Float16)1,
                     (_Float16)1, (_Float16)1, (_Float16)1, (_Float16)1};
  const h16 zero16 = {};

  f32x4 acc[4][4] = {};

  for (int c = 0; c < 9; ++c) {
    int g;
    bool skipc;
    if (c < 8) { g = sp + c * 8; skipc = false; }          // spline chunks 0..63
    else { if (sp >= 4) break; g = 64 + sp; skipc = true; } // skip chunks 64..67

    __syncthreads();  // protect LDS from previous chunk's readers

    // ---- stage W chunk: 32 KiB, [p][o] granules, linear ----
    {
      const char* gsrc = (const char*)wpp + (size_t)g * CHUNK_BYTES + wid * 8192 + lane * 16;
      char* ldst = smem + wid * 8192;
#pragma unroll
      for (int it = 0; it < 8; ++it)
        llds16(gsrc + it * 1024, ldst + it * 1024);
    }

    // ---- build C tile: [p][row] granules ----
    if (!skipc) {
      const int ib = g * 8;
#pragma unroll
      for (int hh = 0; hh < 2; ++hh) {
        const int il = wid * 2 + hh;
#pragma unroll
        for (int rh = 0; rh < 2; ++rh) {
          const int r = lane + rh * 64;
          const float xv = (float)xt[(size_t)(ib + il) * BTOT + b0 + r];
          float t = fminf(fmaxf((xv + 3.0f) * (1.0f / 6.0f), 0.0f), 1.0f);
          const float pos = t * 15.0f;
          const _Float16 ph = (_Float16)pos;
          h16 pv;
#pragma unroll
          for (int q = 0; q < 16; ++q) pv[q] = ph;
          h16 d = __builtin_elementwise_abs(pv - iota16);
          h16 cc = __builtin_elementwise_max(one16 - d, zero16);
          char* base = smem + CBASE + (2 * il) * 2048 + r * 16;
          *(uint4*)base = ((const uint4*)&cc)[0];
          *(uint4*)(base + 2048) = ((const uint4*)&cc)[1];
        }
      }
    } else {
      const int ioff = (g - 64) * 128;
#pragma unroll
      for (int pp = 0; pp < 4; ++pp) {
        const int p = wid * 4 + pp;
#pragma unroll
        for (int rh = 0; rh < 2; ++rh) {
          const int r = lane + rh * 64;
          const float* src = x + (size_t)(b0 + r) * DIN + ioff + p * 8;
          const float4 v0 = ((const float4*)src)[0];
          const float4 v1 = ((const float4*)src)[1];
          uint4 pk;
          pk.x = f2h(v0.x) | ((unsigned)f2h(v0.y) << 16);
          pk.y = f2h(v0.z) | ((unsigned)f2h(v0.w) << 16);
          pk.z = f2h(v1.x) | ((unsigned)f2h(v1.y) << 16);
          pk.w = f2h(v1.z) | ((unsigned)f2h(v1.w) << 16);
          *(uint4*)(smem + CBASE + p * 2048 + r * 16) = pk;
        }
      }
    }
    __syncthreads();

    // ---- MFMA: 4 K32-steps x 16 mfma/wave ----
#pragma unroll
    for (int ks = 0; ks < 4; ++ks) {
      const int slab = (ks * 4 + lq) * 2048 + lr * 16;
      half8 af[4], bf[4];
#pragma unroll
      for (int mt = 0; mt < 4; ++mt)
        af[mt] = *(const half8*)(smem + CBASE + slab + (wm * 64 + mt * 16) * 16);
#pragma unroll
      for (int nt = 0; nt < 4; ++nt)
        bf[nt] = *(const half8*)(smem + slab + (wn * 64 + nt * 16) * 16);
#pragma unroll
      for (int mt = 0; mt < 4; ++mt)
#pragma unroll
        for (int nt = 0; nt < 4; ++nt)
          acc[mt][nt] = __builtin_amdgcn_mfma_f32_16x16x32_f16(af[mt], bf[nt], acc[mt][nt], 0, 0, 0);
    }
  }

  // ---- epilogue: atomic accumulate across k-splits; bias on split 0 ----
#pragma unroll
  for (int nt = 0; nt < 4; ++nt) {
    const int col = wn * 64 + nt * 16 + lr;
    const float bv = (sp == 0) ? bias[col] : 0.0f;
#pragma unroll
    for (int mt = 0; mt < 4; ++mt) {
      const int row0 = b0 + wm * 64 + mt * 16 + lq * 4;
#pragma unroll
      for (int r = 0; r < 4; ++r)
        atomicAdd(out + (size_t)(row0 + r) * DOUT + col, acc[mt][nt][r] + bv);
    }
  }
}

// ---------------- safety-net naive kernel (only if ws too small) ----------------
__global__ void kan_naive(const float* __restrict__ x, const float* __restrict__ w,
                          const float* __restrict__ skw, const float* __restrict__ bias,
                          float* __restrict__ out) {
  const int b = blockIdx.x;
  const int o = threadIdx.x;
  float acc = bias[o];
  for (int i = 0; i < DIN; ++i) {
    float xv = x[(size_t)b * DIN + i];
    float t = fminf(fmaxf((xv + 3.0f) * (1.0f / 6.0f), 0.0f), 1.0f);
    float p = t * 15.0f;
    float fi = floorf(p);
    int i0 = (int)fi;
    int i1 = (i0 < 15) ? i0 + 1 : 15;
    float f = p - fi;
    const float* wr = &w[((size_t)o * DIN + i) * 16];
    acc += (1.0f - f) * wr[i0] + f * wr[i1] + xv * skw[(size_t)o * DIN + i];
  }
  out[(size_t)b * DOUT + o] = acc;
}

extern "C" void kernel_launch(void* const* d_in, const int* in_sizes, int n_in,
                              void* d_out, int out_size, void* d_ws, size_t ws_size,
                              hipStream_t stream) {
  const float* x    = (const float*)d_in[0];
  const float* w    = (const float*)d_in[1];  // (128, 512, 16) fp32
  const float* skw  = (const float*)d_in[2];  // (128, 512) fp32
  const float* bias = (const float*)d_in[3];  // (128,) fp32
  float* out = (float*)d_out;                 // (8192, 128) fp32

  const size_t xt_bytes = (size_t)DIN * BTOT * sizeof(_Float16);      // 8 MiB
  const size_t wpp_bytes = (size_t)NCHUNK * CHUNK_BYTES;              // 2.125 MiB
  if (ws_size < xt_bytes + wpp_bytes) {
    kan_naive<<<BTOT, DOUT, 0, stream>>>(x, w, skw, bias, out);
    return;
  }

  _Float16* xt = (_Float16*)d_ws;
  unsigned short* wpp = (unsigned short*)((char*)d_ws + xt_bytes);

  (void)hipMemsetAsync(d_out, 0, (size_t)out_size * sizeof(float), stream);
  build_wpp<<<NCHUNK * 2048 / 256, 256, 0, stream>>>(w, skw, wpp);
  xpose<<<dim3(DIN / 32, BTOT / 32), 256, 0, stream>>>(x, xt);
  kan_mfma<<<(BTOT / BM) * NSPL, 256, 0, stream>>>(x, xt, wpp, bias, out);
}